// Round 8
// baseline (659.743 us; speedup 1.0000x reference)
//
#include <hip/hip_runtime.h>

// Problem constants (fixed by the reference file)
#define BATCH   8
#define NVERT   50000
#define CIN     32
#define LSP     9
#define COUT    64
#define MVERT   12500
#define NNZ     37500

#define NFRAG   2304           // 9 s * 4 g * 64 lanes (B fragments)
#define OUTDW   (BATCH * MVERT * COUT)

#define TILE_T  128            // tasks per block (32 per wave, 2 M-tiles)
#define TPB     293            // ceil(37500/128)
#define NTILE   (BATCH * TPB)  // 2344 compute tiles

// ONE persistent kernel: 768 blocks = 256 CU x 3 blocks/CU, the exact device
// capacity under __launch_bounds__(256,3) (hard <=170 VGPR guarantee, 1 KB
// LDS). Co-residency is therefore guaranteed -> the r4/r5-proven gbar global
// barrier is deadlock-free. Rationale: across r0-r7, every dispatch was
// individually <58 us yet totals were 172-205 us -- >=70 us lived at graph-
// node boundaries (r5: 3 dispatches, sum<117, total 186). Fusing all phases
// into one launch deletes those boundaries entirely.
#define NB   768
#define NBT  (NB * 256)        // 196,608 threads

#define XVEC8  1600000         // 12.8M floats of x, in groups of 8
#define OUTV4  (OUTDW / 4)
#define SCANB  49              // 49*256 = 12544 >= MVERT

typedef __attribute__((ext_vector_type(8))) short  short8;
typedef __attribute__((ext_vector_type(4))) float  floatx4;

static __device__ __forceinline__ unsigned short f2bf(float f) {
    union { float f; unsigned int u; } c; c.f = f;
    unsigned int u = c.u;
    return (unsigned short)((u + 0x7fffu + ((u >> 16) & 1u)) >> 16);
}

// scan partials (device globals; rewritten before every use each launch)
__device__ int g_bsum[64];

// software global barrier among NB co-resident blocks (r4/r5-proven).
// Agent-scope acq/rel: stores made before the barrier by any block are
// visible to every block after it (release flushes, acquire invalidates
// across the non-coherent per-XCD L2s).
static __device__ __forceinline__ void gbar(int* cnt, int target) {
    __syncthreads();
    if (threadIdx.x == 0) {
        __hip_atomic_fetch_add(cnt, 1, __ATOMIC_RELEASE, __HIP_MEMORY_SCOPE_AGENT);
        while (__hip_atomic_load(cnt, __ATOMIC_ACQUIRE, __HIP_MEMORY_SCOPE_AGENT) < target)
            __builtin_amdgcn_s_sleep(2);
    }
    __syncthreads();
}

__global__ __launch_bounds__(256, 3)
void fused_kernel(const float* __restrict__ x, const float* __restrict__ w,
                  const float* __restrict__ bias,
                  const int* __restrict__ rows, const int* __restrict__ cols,
                  const float* __restrict__ vals, const int* __restrict__ spiral,
                  unsigned short* __restrict__ x16, unsigned short* __restrict__ wp,
                  float* __restrict__ out,
                  int* __restrict__ hist, int* __restrict__ off2,
                  int* __restrict__ rows_s, float* __restrict__ vals_s,
                  unsigned short* __restrict__ tidx, int* __restrict__ barcnt)
{
    __shared__ int sh[256];
    const int blk = blockIdx.x;
    const int tid = threadIdx.x;
    const int gid = blk * 256 + tid;

    // ================= phase A: precast x | zero out | pack W | zero hist
    for (int v = gid; v < XVEC8; v += NBT) {
        const size_t base = (size_t)v * 8;
        const float4* s = (const float4*)(x + base);
        float4 a = s[0], c = s[1];
        unsigned short t[8];
        t[0]=f2bf(a.x); t[1]=f2bf(a.y); t[2]=f2bf(a.z); t[3]=f2bf(a.w);
        t[4]=f2bf(c.x); t[5]=f2bf(c.y); t[6]=f2bf(c.z); t[7]=f2bf(c.w);
        *(uint4*)(x16 + base) = *(uint4*)t;
    }
    for (int v = gid; v < OUTV4; v += NBT)
        *(uint4*)(out + (size_t)v * 4) = (uint4){0, 0, 0, 0};
    if (gid < NFRAG) {
        // B-frag f=(s*4+g)*64+lane holds W[s*32+(lane>>4)*8+j][g*16+(lane&15)]
        const int f = gid;
        int s = f >> 8, g = (f >> 6) & 3, lane = f & 63;
        int k0 = s * 32 + (lane >> 4) * 8, col = g * 16 + (lane & 15);
        unsigned short t[8];
        #pragma unroll
        for (int j = 0; j < 8; ++j)
            t[j] = f2bf(w[(size_t)(k0 + j) * COUT + col]);
        ((uint4*)wp)[f] = *(uint4*)t;
    }
    if (gid < MVERT) hist[gid] = 0;
    gbar(barcnt, 1 * NB);

    // ================= phase B: histogram of rows
    if (gid < NNZ) atomicAdd(&hist[rows[gid]], 1);
    gbar(barcnt, 2 * NB);

    // ================= phase C1: block-local scan (blocks 0..48)
    if (blk < SCANB) {
        const int v = (gid < MVERT) ? hist[gid] : 0;
        sh[tid] = v;
        __syncthreads();
        #pragma unroll
        for (int d = 1; d < 256; d <<= 1) {
            int u = (tid >= d) ? sh[tid - d] : 0;
            __syncthreads();
            sh[tid] += u;
            __syncthreads();
        }
        const int incl = sh[tid];
        if (gid < MVERT) off2[gid] = incl - v;      // local exclusive
        if (tid == 255) g_bsum[blk] = incl;
    }
    gbar(barcnt, 3 * NB);

    // ================= phase C2: each scan-block adds its own prefix
    if (blk < SCANB) {
        int pre = 0;
        for (int k = 0; k < blk; ++k) pre += g_bsum[k];
        if (gid < MVERT) off2[gid] += pre;
    }
    gbar(barcnt, 4 * NB);

    // ================= phase D: scatter into row-sorted order + packed tidx
    if (gid < NNZ) {
        const int z = gid;
        int r = rows[z];
        int c = cols[z];
        int pos = atomicAdd(&off2[r], 1);
        rows_s[pos] = r;
        vals_s[pos] = vals[z];
        unsigned short t[16];
        #pragma unroll
        for (int s = 0; s < 9; ++s) t[s] = (unsigned short)spiral[c * LSP + s];
        #pragma unroll
        for (int s = 9; s < 16; ++s) t[s] = 0;
        uint4* dst = (uint4*)(tidx + (size_t)pos * 16);
        dst[0] = *(uint4*)t;
        dst[1] = *(uint4*)(t + 8);
    }
    gbar(barcnt, 5 * NB);

    // ================= phase E: main compute, grid-striding the 2344 tiles.
    // Body byte-identical to the thrice-proven r0 kernel (52.6-54.4 us);
    // 768 resident blocks = same concurrency as r0's 3-blocks/CU steady state.
    const int w_  = tid >> 6;
    const int lane = tid & 63;
    const int quad = lane >> 4;
    const int m16  = lane & 15;

    float bs[4];
    #pragma unroll
    for (int g = 0; g < 4; ++g) bs[g] = bias[g * 16 + m16];

    for (int t = blk; t < NTILE; t += NB) {
        const int b    = t & 7;        // XCD swizzle: batch <-> XCD
        const int tile = t >> 3;
        const int z0w  = tile * TILE_T + 32 * w_;

        const int   zc   = min(z0w + (lane & 31), NNZ - 1);
        const int   rowv = rows_s[zc];
        const float valv = vals_s[zc];
        const uint4 p0 = *(const uint4*)(tidx + (size_t)zc * 16);
        const unsigned int p1 = *(const unsigned int*)(tidx + (size_t)zc * 16 + 8);
        int idx[9];
        idx[0] = p0.x & 0xffff;  idx[1] = p0.x >> 16;
        idx[2] = p0.y & 0xffff;  idx[3] = p0.y >> 16;
        idx[4] = p0.z & 0xffff;  idx[5] = p0.z >> 16;
        idx[6] = p0.w & 0xffff;  idx[7] = p0.w >> 16;
        idx[8] = p1 & 0xffff;

        const unsigned short* xb = x16 + (size_t)b * NVERT * CIN;

        short8 A[2][9];
        #pragma unroll
        for (int s = 0; s < 9; ++s) {
            #pragma unroll
            for (int mt = 0; mt < 2; ++mt) {
                int tix = __shfl(idx[s], mt * 16 + m16);
                A[mt][s] = *(const short8*)(xb + (size_t)tix * CIN + quad * 8);
            }
        }

        floatx4 acc[2][4];
        #pragma unroll
        for (int mt = 0; mt < 2; ++mt)
            #pragma unroll
            for (int g = 0; g < 4; ++g) acc[mt][g] = (floatx4){0.f, 0.f, 0.f, 0.f};

        #pragma unroll
        for (int s = 0; s < 9; ++s) {
            short8 bf[4];
            #pragma unroll
            for (int g = 0; g < 4; ++g)
                bf[g] = *(const short8*)(wp + (size_t)((s * 4 + g) * 64 + lane) * 8);
            #pragma unroll
            for (int mt = 0; mt < 2; ++mt)
                #pragma unroll
                for (int g = 0; g < 4; ++g)
                    acc[mt][g] = __builtin_amdgcn_mfma_f32_16x16x32_bf16(A[mt][s], bf[g], acc[mt][g], 0, 0, 0);
        }

        float* outb = out + (size_t)b * MVERT * COUT;

        #pragma unroll
        for (int mt = 0; mt < 2; ++mt) {
            int   rr[4]; float vv[4]; bool val[4];
            #pragma unroll
            for (int r = 0; r < 4; ++r) {
                const int tsk = mt * 16 + quad * 4 + r;    // C row = quad*4 + reg
                rr[r]  = __shfl(rowv, tsk);
                vv[r]  = __shfl(valv, tsk);
                val[r] = (z0w + tsk) < NNZ;
            }
            bool emit[4];   // last element of an equal-row run
            #pragma unroll
            for (int r = 0; r < 4; ++r)
                emit[r] = (r == 3) || (!val[r + 1 > 3 ? 3 : r + 1]) || (rr[r + 1 > 3 ? 3 : r + 1] != rr[r]);
            #pragma unroll
            for (int g = 0; g < 4; ++g) {
                const int ch = g * 16 + m16;
                float s = 0.0f;
                #pragma unroll
                for (int r = 0; r < 4; ++r) {
                    if (val[r]) {
                        float y = acc[mt][g][r] + bs[g];
                        y = (y > 0.0f) ? y : (__expf(y) - 1.0f);
                        s += y * vv[r];
                        if (emit[r]) {
                            atomicAdd(outb + (size_t)rr[r] * COUT + ch, s);
                            s = 0.0f;
                        }
                    }
                }
            }
        }
    }
}

extern "C" void kernel_launch(void* const* d_in, const int* in_sizes, int n_in,
                              void* d_out, int out_size, void* d_ws, size_t ws_size,
                              hipStream_t stream) {
    const float* x      = (const float*)d_in[0];
    const float* w      = (const float*)d_in[1];
    const float* bias   = (const float*)d_in[2];
    const float* vals   = (const float*)d_in[3];
    const int*   spiral = (const int*)d_in[4];
    const int*   rows   = (const int*)d_in[5];
    const int*   cols   = (const int*)d_in[6];
    float* out = (float*)d_out;

    // ws layout (hist + barcnt contiguous -> one tiny memset zeroes both)
    char* base = (char*)d_ws;
    unsigned short* wp     = (unsigned short*)(base);                    //    36,864 B
    unsigned short* x16    = (unsigned short*)(base + 36864);            // 25,600,000 B
    int*            hist   = (int*)(base + 25636864);                    //     50,000 B
    int*            barcnt = (int*)(base + 25686864);                    //         16 B
    int*            off2   = (int*)(base + 25686880);                    //     50,000 B
    int*            rows_s = (int*)(base + 25736880);                    //    150,000 B
    float*          vals_s = (float*)(base + 25886880);                  //    150,000 B
    unsigned short* tidx   = (unsigned short*)(base + 26186912);         //  1,200,000 B

    hipMemsetAsync(hist, 0, MVERT * sizeof(int) + 16, stream);   // hist + barcnt

    fused_kernel<<<NB, 256, 0, stream>>>(x, w, bias, rows, cols, vals, spiral,
                                         x16, wp, out, hist, off2,
                                         rows_s, vals_s, tidx, barcnt);
}

// Round 9
// 182.354 us; speedup vs baseline: 3.6179x; 3.6179x over previous
//
#include <hip/hip_runtime.h>

// Problem constants (fixed by the reference file)
#define BATCH   8
#define NVERT   50000
#define CIN     32
#define LSP     9
#define COUT    64
#define MVERT   12500
#define NNZ     37500

#define NFRAG   2304           // 9 s * 4 g * 64 lanes (B fragments)
#define OUTDW   (BATCH * MVERT * COUT)

#define TILE_T  128            // tasks per block (32 per wave, 2 M-tiles)
#define TPB     293            // ceil(37500/128)

#define PRE_BLOCKS   6250
#define PACK_BLOCKS  9
#define ZERO_BLOCKS  6250
#define TIDX_BLOCKS  147       // 147*256 = 37632 >= NNZ

typedef __attribute__((ext_vector_type(8))) short  short8;
typedef __attribute__((ext_vector_type(4))) float  floatx4;

static __device__ __forceinline__ unsigned short f2bf(float f) {
    union { float f; unsigned int u; } c; c.f = f;
    unsigned int u = c.u;
    return (unsigned short)((u + 0x7fffu + ((u >> 16) & 1u)) >> 16);
}

// ---- k1: precast x | pack W | zero out | build per-task packed spiral
// indices in ORIGINAL task order (no sort). The entire hist+scan+scatter
// pipeline (2 extra dispatches + memset + ~40 us work + ~2 boundaries) is
// deleted: its only purpose was run-compression halving epilogue atomics,
// and rounds 1/6 showed atomic reduction never sped the main kernel up.
// This round tests that hypothesis at 2x dose while removing ~65 us of
// setup+boundary cost. Grid shape = r2's best-measured prep (12.6k blocks).
__global__ __launch_bounds__(256)
void prep_kernel(const float* __restrict__ x, const float* __restrict__ w,
                 const int* __restrict__ cols, const int* __restrict__ spiral,
                 unsigned short* __restrict__ x16, unsigned short* __restrict__ wp,
                 float* __restrict__ out, unsigned short* __restrict__ tidx)
{
    const int blk = blockIdx.x;
    const int tid = threadIdx.x;
    if (blk < PRE_BLOCKS) {
        const size_t base = ((size_t)blk * 256 + tid) * 8;
        const float4* s = (const float4*)(x + base);
        float4 a = s[0], c = s[1];
        unsigned short t[8];
        t[0]=f2bf(a.x); t[1]=f2bf(a.y); t[2]=f2bf(a.z); t[3]=f2bf(a.w);
        t[4]=f2bf(c.x); t[5]=f2bf(c.y); t[6]=f2bf(c.z); t[7]=f2bf(c.w);
        *(uint4*)(x16 + base) = *(uint4*)t;
    } else if (blk < PRE_BLOCKS + PACK_BLOCKS) {
        // B-frag f=(s*4+g)*64+lane holds W[s*32+(lane>>4)*8+j][g*16+(lane&15)]
        const int f = (blk - PRE_BLOCKS) * 256 + tid;
        if (f < NFRAG) {
            int s = f >> 8, g = (f >> 6) & 3, lane = f & 63;
            int k0 = s * 32 + (lane >> 4) * 8, col = g * 16 + (lane & 15);
            unsigned short t[8];
            #pragma unroll
            for (int j = 0; j < 8; ++j)
                t[j] = f2bf(w[(size_t)(k0 + j) * COUT + col]);
            ((uint4*)wp)[f] = *(uint4*)t;
        }
    } else if (blk < PRE_BLOCKS + PACK_BLOCKS + ZERO_BLOCKS) {
        const size_t base = ((size_t)(blk - PRE_BLOCKS - PACK_BLOCKS) * 256 + tid) * 4;
        if (base < OUTDW) *(uint4*)(out + base) = (uint4){0, 0, 0, 0};
    } else {
        // build packed per-task spiral indices, task z in original order
        const int z = (blk - PRE_BLOCKS - PACK_BLOCKS - ZERO_BLOCKS) * 256 + tid;
        if (z < NNZ) {
            const int c = cols[z];
            unsigned short t[16];
            #pragma unroll
            for (int s = 0; s < 9; ++s) t[s] = (unsigned short)spiral[c * LSP + s];
            #pragma unroll
            for (int s = 9; s < 16; ++s) t[s] = 0;
            uint4* dst = (uint4*)(tidx + (size_t)z * 16);
            dst[0] = *(uint4*)t;
            dst[1] = *(uint4*)(t + 8);
        }
    }
}

// ---- k2: fused gather+GEMM+ELU+scale + scatter-add, UNSORTED task order.
// Body byte-identical to the thrice-measured 52.6-54.4 us r0 kernel except:
// rows_s/vals_s -> rows/vals (still coalesced loads), tidx indexed by raw
// task id. Run-compression logic kept (rarely fires unsorted -> ~2x atomic
// ops). If this kernel holds ~55-70 us, atomics are definitively not the
// limiter and the sort pipeline never paid for itself.
__global__ __launch_bounds__(256, 3)
void spiral_mfma12_kernel(const unsigned short* __restrict__ x16,
                          const unsigned short* __restrict__ wp,
                          const float* __restrict__ bias,
                          const unsigned short* __restrict__ tidx,
                          const int* __restrict__ rows,
                          const float* __restrict__ vals,
                          float* __restrict__ out)
{
    const int bid  = blockIdx.x;
    const int b    = bid & 7;          // XCD swizzle: batch <-> XCD (x16/out L2-local)
    const int tile = bid >> 3;
    const int tid  = threadIdx.x;
    const int w    = tid >> 6;
    const int lane = tid & 63;
    const int quad = lane >> 4;
    const int m16  = lane & 15;
    const int z0w  = tile * TILE_T + 32 * w;   // wave's first task index

    // per-lane task metadata: lane L carries task z0w + (L&31) (coalesced)
    const int   zc   = min(z0w + (lane & 31), NNZ - 1);
    const int   rowv = rows[zc];
    const float valv = vals[zc];
    const uint4 p0 = *(const uint4*)(tidx + (size_t)zc * 16);
    const unsigned int p1 = *(const unsigned int*)(tidx + (size_t)zc * 16 + 8);
    int idx[9];
    idx[0] = p0.x & 0xffff;  idx[1] = p0.x >> 16;
    idx[2] = p0.y & 0xffff;  idx[3] = p0.y >> 16;
    idx[4] = p0.z & 0xffff;  idx[5] = p0.z >> 16;
    idx[6] = p0.w & 0xffff;  idx[7] = p0.w >> 16;
    idx[8] = p1 & 0xffff;

    const unsigned short* xb = x16 + (size_t)b * NVERT * CIN;

    // ---- all A-fragment gathers up front: one latency round-trip
    short8 A[2][9];
    #pragma unroll
    for (int s = 0; s < 9; ++s) {
        #pragma unroll
        for (int mt = 0; mt < 2; ++mt) {
            int tix = __shfl(idx[s], mt * 16 + m16);
            A[mt][s] = *(const short8*)(xb + (size_t)tix * CIN + quad * 8);
        }
    }

    floatx4 acc[2][4];
    #pragma unroll
    for (int mt = 0; mt < 2; ++mt)
        #pragma unroll
        for (int g = 0; g < 4; ++g) acc[mt][g] = (floatx4){0.f, 0.f, 0.f, 0.f};

    #pragma unroll
    for (int s = 0; s < 9; ++s) {
        short8 bf[4];
        #pragma unroll
        for (int g = 0; g < 4; ++g)
            bf[g] = *(const short8*)(wp + (size_t)((s * 4 + g) * 64 + lane) * 8);
        #pragma unroll
        for (int mt = 0; mt < 2; ++mt)
            #pragma unroll
            for (int g = 0; g < 4; ++g)
                acc[mt][g] = __builtin_amdgcn_mfma_f32_16x16x32_bf16(A[mt][s], bf[g], acc[mt][g], 0, 0, 0);
    }

    // ---- epilogue: register run-compression (mostly no-op unsorted) + atomics
    float bs[4];
    #pragma unroll
    for (int g = 0; g < 4; ++g) bs[g] = bias[g * 16 + m16];
    float* outb = out + (size_t)b * MVERT * COUT;

    #pragma unroll
    for (int mt = 0; mt < 2; ++mt) {
        int   rr[4]; float vv[4]; bool val[4];
        #pragma unroll
        for (int r = 0; r < 4; ++r) {
            const int tsk = mt * 16 + quad * 4 + r;        // C row = quad*4 + reg
            rr[r]  = __shfl(rowv, tsk);
            vv[r]  = __shfl(valv, tsk);
            val[r] = (z0w + tsk) < NNZ;
        }
        bool emit[4];   // last element of an equal-row run
        #pragma unroll
        for (int r = 0; r < 4; ++r)
            emit[r] = (r == 3) || (!val[r + 1 > 3 ? 3 : r + 1]) || (rr[r + 1 > 3 ? 3 : r + 1] != rr[r]);
        #pragma unroll
        for (int g = 0; g < 4; ++g) {
            const int ch = g * 16 + m16;
            float s = 0.0f;
            #pragma unroll
            for (int r = 0; r < 4; ++r) {
                if (val[r]) {
                    float y = acc[mt][g][r] + bs[g];
                    y = (y > 0.0f) ? y : (__expf(y) - 1.0f);
                    s += y * vv[r];
                    if (emit[r]) {
                        atomicAdd(outb + (size_t)rr[r] * COUT + ch, s);
                        s = 0.0f;
                    }
                }
            }
        }
    }
}

extern "C" void kernel_launch(void* const* d_in, const int* in_sizes, int n_in,
                              void* d_out, int out_size, void* d_ws, size_t ws_size,
                              hipStream_t stream) {
    const float* x      = (const float*)d_in[0];
    const float* w      = (const float*)d_in[1];
    const float* bias   = (const float*)d_in[2];
    const float* vals   = (const float*)d_in[3];
    const int*   spiral = (const int*)d_in[4];
    const int*   rows   = (const int*)d_in[5];
    const int*   cols   = (const int*)d_in[6];
    float* out = (float*)d_out;

    // ws layout
    char* base = (char*)d_ws;
    unsigned short* wp     = (unsigned short*)(base);                    //    36,864 B
    unsigned short* x16    = (unsigned short*)(base + 36864);            // 25,600,000 B
    unsigned short* tidx   = (unsigned short*)(base + 26186912);         //  1,200,000 B

    const int prep_grid = PRE_BLOCKS + PACK_BLOCKS + ZERO_BLOCKS + TIDX_BLOCKS;
    prep_kernel<<<prep_grid, 256, 0, stream>>>(x, w, cols, spiral,
                                               x16, wp, out, tidx);
    spiral_mfma12_kernel<<<BATCH * TPB, 256, 0, stream>>>(x16, wp, bias, tidx,
                                                          rows, vals, out);
}